// Round 9
// baseline (429.683 us; speedup 1.0000x reference)
//
#include <hip/hip_runtime.h>

// Problem constants
#define BATCH 4
#define NSEQ 2048
#define MSEQ 2048
#define DIM 1024
#define HEADS 16
#define DHEAD 64
#define INNER 1024
#define KVLEN 2049          // null token + MSEQ
#define KVPAD 2176          // 17 * 128

typedef unsigned short u16;
typedef unsigned int u32;
typedef __bf16 bf16x8 __attribute__((ext_vector_type(8)));
typedef float f32x4 __attribute__((ext_vector_type(4)));

__device__ inline u16 f2bf(float f) {
  u32 u = __builtin_bit_cast(u32, f);
  u = (u + 0x7fffu + ((u >> 16) & 1u)) >> 16;
  return (u16)u;
}
__device__ inline float bf2f(u16 x) {
  return __builtin_bit_cast(float, (u32)x << 16);
}
// packed bf16 convert: lo -> D[15:0], hi -> D[31:16] (RNE)
__device__ inline u32 pk_bf16(float lo, float hi) {
  u32 r;
  asm("v_cvt_pk_bf16_f32 %0, %1, %2" : "=v"(r) : "v"(lo), "v"(hi));
  return r;
}

__device__ __forceinline__ void gld_lds16(const void* g, void* l) {
  __builtin_amdgcn_global_load_lds(
      (const __attribute__((address_space(1))) void*)g,
      (__attribute__((address_space(3))) void*)l, 16, 0, 0);
}

// ---------------- LayerNorm (row of 1024), output bf16 or fp32 ----------------
template <bool OUT_BF16>
__global__ __launch_bounds__(256) void ln_kernel(const float* __restrict__ x,
                                                 const float* __restrict__ g,
                                                 void* __restrict__ out) {
  const int row = blockIdx.x;
  const int t = threadIdx.x;
  const float4 v = ((const float4*)(x + (size_t)row * 1024))[t];
  float sum = v.x + v.y + v.z + v.w;
  float sq = v.x * v.x + v.y * v.y + v.z * v.z + v.w * v.w;
  for (int m = 1; m < 64; m <<= 1) {
    sum += __shfl_xor(sum, m, 64);
    sq += __shfl_xor(sq, m, 64);
  }
  __shared__ float red[8];
  const int w = t >> 6, l = t & 63;
  if (l == 0) { red[w] = sum; red[4 + w] = sq; }
  __syncthreads();
  sum = red[0] + red[1] + red[2] + red[3];
  sq = red[4] + red[5] + red[6] + red[7];
  const float mean = sum * (1.0f / 1024.0f);
  const float var = sq * (1.0f / 1024.0f) - mean * mean;
  const float rstd = rsqrtf(var + 1e-5f);
  const float4 gv = ((const float4*)g)[t];
  float o0 = (v.x - mean) * rstd * gv.x;
  float o1 = (v.y - mean) * rstd * gv.y;
  float o2 = (v.z - mean) * rstd * gv.z;
  float o3 = (v.w - mean) * rstd * gv.w;
  if (OUT_BF16) {
    ushort4 ov;
    ov.x = f2bf(o0); ov.y = f2bf(o1); ov.z = f2bf(o2); ov.w = f2bf(o3);
    ((ushort4*)((u16*)out + (size_t)row * 1024))[t] = ov;
  } else {
    float4 ov;
    ov.x = o0; ov.y = o1; ov.z = o2; ov.w = o3;
    ((float4*)((float*)out + (size_t)row * 1024))[t] = ov;
  }
}

// ---------------- fp32 -> bf16 cast (vectorized by 4) ----------------
__global__ __launch_bounds__(256) void cast_bf16(const float* __restrict__ in,
                                                 u16* __restrict__ out, int n4) {
  int i = blockIdx.x * 256 + threadIdx.x;
  if (i < n4) {
    float4 v = ((const float4*)in)[i];
    ushort4 o;
    o.x = f2bf(v.x); o.y = f2bf(v.y); o.z = f2bf(v.z); o.w = f2bf(v.w);
    ((ushort4*)out)[i] = o;
  }
}

// ---------------- W[K][N] fp32 -> WT[N][K] bf16 (tiled transpose) ----------------
__global__ __launch_bounds__(256) void transpose_cast(const float* __restrict__ W,
                                                      u16* __restrict__ WT, int K, int N) {
  __shared__ float tile[32][33];
  const int tx = threadIdx.x & 31, ty = threadIdx.x >> 5;  // ty 0..7
  const int k0 = blockIdx.y * 32, n0 = blockIdx.x * 32;
  for (int r = ty; r < 32; r += 8) tile[r][tx] = W[(size_t)(k0 + r) * N + n0 + tx];
  __syncthreads();
  for (int r = ty; r < 32; r += 8) WT[(size_t)(n0 + r) * K + k0 + tx] = f2bf(tile[tx][r]);
}

// ---------------- bf16 GEMM: C = A[M][K] @ Bt[N][K]^T ----------------
// MODE 0: fp32 C row-major. MODE 1: bf16 C row-major.
// MODE 2: fused q_post -> l2norm(head)*scale*8, write qn[b,h,n,64].
// MODE 3: fused kv post -> heads 0..15: l2norm*k_scale -> kn[b,h,m+1,64];
//                          heads 16..31: plain bf16 -> aux[row][ (h-16)*64+d ].
template <int MODE>
__global__ __launch_bounds__(256) void gemm_bt(const u16* __restrict__ A,
                                               const u16* __restrict__ Bt,
                                               void* __restrict__ Cv,
                                               int M, int N, int K,
                                               const float* __restrict__ scale,
                                               u16* __restrict__ aux) {
  __shared__ __align__(16) u16 As[128 * 32];
  __shared__ __align__(16) u16 Bs[128 * 32];
  const int t = threadIdx.x;
  const int w = t >> 6, l = t & 63, l15 = l & 15, lq = l >> 4;
  const int m0 = blockIdx.y * 128, n0 = blockIdx.x * 128;
  const int wm = (w >> 1) * 64, wn = (w & 1) * 64;
  const int lr = l >> 2;           // 0..15 row-within-chunk
  const int lo = (l & 3) * 8;      // u16 offset within row: 0,8,16,24
  f32x4 acc[4][4] = {};
  for (int k0 = 0; k0 < K; k0 += 32) {
#pragma unroll
    for (int it = 0; it < 2; it++) {
      const int row = (w * 2 + it) * 16 + lr;   // 0..127
      gld_lds16(&A[(size_t)(m0 + row) * K + k0 + lo], &As[row * 32 + lo]);
      gld_lds16(&Bt[(size_t)(n0 + row) * K + k0 + lo], &Bs[row * 32 + lo]);
    }
    __syncthreads();
    bf16x8 af[4], bfr[4];
#pragma unroll
    for (int i = 0; i < 4; i++) af[i] = *(bf16x8*)&As[(wm + i * 16 + l15) * 32 + lq * 8];
#pragma unroll
    for (int j = 0; j < 4; j++) bfr[j] = *(bf16x8*)&Bs[(wn + j * 16 + l15) * 32 + lq * 8];
#pragma unroll
    for (int i = 0; i < 4; i++)
#pragma unroll
      for (int j = 0; j < 4; j++)
        acc[i][j] = __builtin_amdgcn_mfma_f32_16x16x32_bf16(af[i], bfr[j], acc[i][j], 0, 0, 0);
    __syncthreads();
  }

  if (MODE <= 1) {
#pragma unroll
    for (int i = 0; i < 4; i++)
#pragma unroll
      for (int j = 0; j < 4; j++)
#pragma unroll
        for (int r = 0; r < 4; r++) {
          const size_t off =
              (size_t)(m0 + wm + i * 16 + lq * 4 + r) * N + n0 + wn + j * 16 + l15;
          if (MODE == 1) ((u16*)Cv)[off] = f2bf(acc[i][j][r]);
          else ((float*)Cv)[off] = acc[i][j][r];
        }
    return;
  }

  const int head = (n0 + wn) >> 6;  // wave-uniform
  if (MODE == 3 && head >= 16) {
    // V columns: plain bf16 into compact aux[row][ (head-16)*64 + d ]
#pragma unroll
    for (int i = 0; i < 4; i++)
#pragma unroll
      for (int j = 0; j < 4; j++)
#pragma unroll
        for (int r = 0; r < 4; r++) {
          const int row = m0 + wm + i * 16 + lq * 4 + r;
          aux[(size_t)row * 1024 + (head - 16) * 64 + j * 16 + l15] = f2bf(acc[i][j][r]);
        }
    return;
  }
  // l2norm over the 64-col head + scale (q: *8)
  float sc[4];
#pragma unroll
  for (int j = 0; j < 4; j++) sc[j] = scale[j * 16 + l15];
  const float mul = (MODE == 2) ? 8.0f : 1.0f;
  u16* outp = (u16*)Cv;
#pragma unroll
  for (int i = 0; i < 4; i++)
#pragma unroll
    for (int r = 0; r < 4; r++) {
      float ss = 0.f;
#pragma unroll
      for (int j = 0; j < 4; j++) ss = fmaf(acc[i][j][r], acc[i][j][r], ss);
#pragma unroll
      for (int m = 1; m < 16; m <<= 1) ss += __shfl_xor(ss, m, 64);
      const float inv = mul / fmaxf(sqrtf(ss), 1e-12f);
      const int row = m0 + wm + i * 16 + lq * 4 + r;
      const int b = row >> 11, n = row & 2047;
      const size_t base = (MODE == 2)
          ? (((size_t)b * 16 + head) * 2048 + n) * 64
          : (((size_t)b * 16 + head) * (size_t)KVPAD + n + 1) * 64;
#pragma unroll
      for (int j = 0; j < 4; j++)
        outp[base + j * 16 + l15] = f2bf(acc[i][j][r] * inv * sc[j]);
    }
}

// ---------------- v post: transpose vg[row][h*64+d] -> vt[b,h,64,KVPAD] ----------------
// The KV (column) index is stored k-PERMUTED within each 128-aligned block
// by the bit-permutation matching the in-register P fragments of attn_kernel:
//   forward g(slot): [s6 s5 s4 s3 s2 s1 s0] -> kv-local [s6 s5 s2 s4 s3 s1 s0]
//   inverse slot(a) = (a & 0x63) | ((a & 0x10) >> 2) | ((a & 0x0C) << 1)
// slot() keeps bits 0,1,5,6 fixed -> it maps every 64-aligned block onto
// itself (required by attn's KVBLK=64 tiling). slot(0)=0, so null_tail
// (null token slot 0, tail zeroing 2049..2175) is unchanged.
__global__ __launch_bounds__(256) void v_post(const u16* __restrict__ vg,
                                              u16* __restrict__ vt) {
  __shared__ u16 tile[64][68];
  const int bh = blockIdx.y, mt = blockIdx.x;
  const int tx = threadIdx.x & 63, ty = threadIdx.x >> 6;
  const int b = bh >> 4, h = bh & 15;
  const int m0 = mt * 64;
  for (int r = ty; r < 64; r += 4)
    tile[tx][r] = vg[(size_t)(b * 2048 + m0 + r) * 1024 + h * 64 + tx];
  __syncthreads();
  const int abs_ = 1 + m0 + tx;
  const int a = abs_ & 127;
  const int slot = (abs_ & ~127) | (a & 0x63) | ((a & 0x10) >> 2) | ((a & 0x0C) << 1);
  for (int d = ty; d < 64; d += 4)
    vt[((size_t)bh * 64 + d) * KVPAD + slot] = tile[d][tx];
}

// ---------------- null token + tail zeroing (256-thread version, R5-verified) ----------------
__global__ __launch_bounds__(256) void null_tail(const float* __restrict__ null_kv,
                                                 const float* __restrict__ k_scale,
                                                 u16* __restrict__ kn, u16* __restrict__ vt) {
  const int bh = blockIdx.x, t = threadIdx.x;
  const int d = t & 63, seg = t >> 6;  // seg 0..3
  if (seg == 0) {  // one full wave: null token (needs 64-lane reduction)
    float nk = null_kv[d];
    float nv = null_kv[64 + d];
    float ss = nk * nk;
    for (int m = 1; m < 64; m <<= 1) ss += __shfl_xor(ss, m, 64);
    float inv = 1.0f / fmaxf(sqrtf(ss), 1e-12f);
    kn[((size_t)bh * KVPAD) * 64 + d] = f2bf(nk * inv * k_scale[d]);
    vt[((size_t)bh * 64 + d) * KVPAD] = f2bf(nv);  // slot(0) == 0
  }
  for (int m = KVLEN + seg; m < KVPAD; m += 4) kn[((size_t)bh * KVPAD + m) * 64 + d] = 0;
  u16* vrow = vt + ((size_t)bh * 64 + d) * KVPAD;
  for (int m = KVLEN + seg; m < KVPAD; m += 4) vrow[m] = 0;
}

// ---------------- flash attention, fixed-max softmax ----------------
// |sim| <= 8 by Cauchy-Schwarz (l2norm'd q,k; scales==1; SCALE=8) -> static max 8.
// Structure (R7/R8-banked): SWAPPED QK^T — mfma(K_frag, Q_frag) gives D = S^T;
// lane (l15,lq) reg r of tile j holds S[q=l15][kv-local=j*16+lq*4+r]. P stays
// in registers (v_cvt_pk_bf16_f32 -> pa frags); V rows g-permuted (v_post);
// lsum on the MFMA pipe via mfma(pa, ones). Staging: global_load_lds, linear
// LDS, source-side bank swizzle slot' = slot ^ (row&7).
// R9 delta: KVBLK 128 -> 64. R8 counters (no pipe >50%, Occ 36%) say the
// kernel is overlap-limited by its 2-barrier/kt lockstep; halving LDS to
// 16 KB doubles resident blocks to 8/CU (32 waves, full occupancy) so other
// blocks cover each barrier drain. Total staging instrs / LDS reads / MFMA
// unchanged (33 tiles x half size); barrier count doubles but each is half
// the wait. g-permutation maps 64-blocks onto themselves (bits 5,6 fixed) so
// v_post/null_tail/mask logic carry over; tile 32 masks to kv-local 0; tile
// 33 (2112..2175, all padding) is never iterated. launch_bounds(256,8) caps
// VGPR at 64 for 8 waves/SIMD (St/p arrays halved -> fits).
// R5 post-mortem: direct-global fragments 3.6x WORSE. R2/R3: 32-q-rows/wave
// variant fails correctness (unlocalized); don't re-attempt without bisection.
__global__ __launch_bounds__(256, 8) void attn_kernel(const u16* __restrict__ qn,
                                                      const u16* __restrict__ kn,
                                                      const u16* __restrict__ vt,
                                                      u16* __restrict__ aout) {
  __shared__ __align__(16) u16 Ks[64 * 64];  // K tile (linear, src-swizzled)
  __shared__ __align__(16) u16 Vs[64 * 64];  // V^T tile (linear, src-swizzled, g-permuted kv)
  const int qt = blockIdx.x, bh = blockIdx.y;
  const int b = bh >> 4, h = bh & 15;
  const int t = threadIdx.x, w = t >> 6, l = t & 63, l15 = l & 15, lq = l >> 4;

  // Q fragments straight from global (loop-invariant); used as MFMA B-operand
  bf16x8 aqf[2];
  {
    const u16* qrow = qn + ((size_t)bh * 2048 + qt * 64 + w * 16 + l15) * 64 + lq * 8;
    aqf[0] = *(const bf16x8*)(qrow);
    aqf[1] = *(const bf16x8*)(qrow + 32);
  }

  // constant ones vector (bf16 1.0 = 0x3F80) for the lsum MFMA
  const uint4 onesu = {0x3F803F80u, 0x3F803F80u, 0x3F803F80u, 0x3F803F80u};
  const bf16x8 vones = __builtin_bit_cast(bf16x8, onesu);

  // swizzled fragment-read slot offsets (u16): slot' = (i*4+lq) ^ (l15&7), i=0..1
  int so[2];
#pragma unroll
  for (int i = 0; i < 2; i++) so[i] = ((i * 4 + lq) ^ (l15 & 7)) * 8;

  // staging: per-lane swizzled GLOBAL source, linear LDS dest (base + lane*16).
  // Both tiles are 64 rows x 64 u16 = 8 KB: 2 gld_lds rounds of 32 rows each.
  // Round i, thread t: row = i*32 + w*8 + (l>>3); 16B slot = (l&7) ^ (l>>3)
  // (row&7 == l>>3 since w*8, i*32 are 0 mod 8).
  const u16* kn_b = kn + (size_t)bh * KVPAD * 64;
  const u16* vt_b = vt + (size_t)bh * 64 * KVPAD;
  const u16* ksrc[2];
  const u16* vsrc[2];
#pragma unroll
  for (int i = 0; i < 2; i++) {
    const int row = i * 32 + w * 8 + (l >> 3);
    const int sl = (l & 7) ^ (l >> 3);
    ksrc[i] = kn_b + row * 64 + sl * 8;
    vsrc[i] = vt_b + (size_t)row * KVPAD + sl * 8;
  }
  u16* kdst = &Ks[w * 512 + l * 8];
  u16* vdst = &Vs[w * 512 + l * 8];

  f32x4 O[4] = {};
  f32x4 lsacc = {};  // lsum[q=lq*4+r] in reg r (all l15 identical)
  const float LOG2E = 1.44269504f;
  const float MBIAS = -8.0f * 1.44269504f;  // exp(s-8) = 2^(s*log2e + MBIAS)

  for (int kt = 0; kt < 33; kt++) {  // 33 of 34 tiles: tile 33 is all padding
    // ---- stage K (64x64) and V^T (64x64) via global_load_lds, src-swizzled ----
#pragma unroll
    for (int i = 0; i < 2; i++) {
      gld_lds16(ksrc[i] + kt * 4096, kdst + i * 2048);
      gld_lds16(vsrc[i] + kt * 64, vdst + i * 2048);
    }
    __syncthreads();  // compiler drains vmcnt before s_barrier

    // ---- S^T = K Q^T (swapped): St[j] lane(l15,lq) reg r = S[q=l15][j*16+lq*4+r] ----
    f32x4 St[4] = {};
    __builtin_amdgcn_s_setprio(1);
#pragma unroll
    for (int ks = 0; ks < 2; ks++)
#pragma unroll
      for (int j = 0; j < 4; j++) {
        bf16x8 ak = *(bf16x8*)&Ks[(j * 16 + l15) * 64 + so[ks]];
        St[j] = __builtin_amdgcn_mfma_f32_16x16x32_bf16(ak, aqf[ks], St[j], 0, 0, 0);
      }
    __builtin_amdgcn_s_setprio(0);

    // ---- P = exp(S - 8) in registers; mask pass uniform-branched; pack pa ----
    float p[4][4];
#pragma unroll
    for (int j = 0; j < 4; j++)
#pragma unroll
      for (int r = 0; r < 4; r++)
        p[j][r] = __builtin_amdgcn_exp2f(fmaf(St[j][r], LOG2E, MBIAS));
    if (kt == 32) {  // uniform branch: only kv-local 0 (global 2048) is valid
#pragma unroll
      for (int j = 0; j < 4; j++)
#pragma unroll
        for (int r = 0; r < 4; r++)
          if ((j | r) != 0) p[j][r] = 0.f;        // compile-time for j|r != 0
      if (lq != 0) p[0][0] = 0.f;                 // lane-dependent only here
    }
    bf16x8 pa[2];
#pragma unroll
    for (int m = 0; m < 2; m++) {
      uint4 pw;
      pw.x = pk_bf16(p[2 * m][0], p[2 * m][1]);
      pw.y = pk_bf16(p[2 * m][2], p[2 * m][3]);
      pw.z = pk_bf16(p[2 * m + 1][0], p[2 * m + 1][1]);
      pw.w = pk_bf16(p[2 * m + 1][2], p[2 * m + 1][3]);
      pa[m] = __builtin_bit_cast(bf16x8, pw);
    }

    // ---- O += P V; lsum += P @ ones (MFMA pipe, no VALU) ----
    __builtin_amdgcn_s_setprio(1);
#pragma unroll
    for (int m = 0; m < 2; m++) {
      lsacc = __builtin_amdgcn_mfma_f32_16x16x32_bf16(pa[m], vones, lsacc, 0, 0, 0);
#pragma unroll
      for (int nt = 0; nt < 4; nt++) {
        bf16x8 bv = *(bf16x8*)&Vs[(nt * 16 + l15) * 64 + so[m]];
        O[nt] = __builtin_amdgcn_mfma_f32_16x16x32_bf16(pa[m], bv, O[nt], 0, 0, 0);
      }
    }
    __builtin_amdgcn_s_setprio(0);
    __syncthreads();  // K/V reads done before next staging overwrites
  }

  // ---- normalize + store (lsacc[r] already in O's register layout) ----
  float inv[4];
#pragma unroll
  for (int r = 0; r < 4; r++) inv[r] = 1.0f / lsacc[r];
#pragma unroll
  for (int nt = 0; nt < 4; nt++)
#pragma unroll
    for (int r = 0; r < 4; r++) {
      int row = qt * 64 + w * 16 + lq * 4 + r;
      int col = h * 64 + nt * 16 + l15;
      float val = O[nt][r] * inv[r];
      aout[((size_t)b * 2048 + row) * 1024 + col] = f2bf(val);
    }
}

// ---------------- host launch ----------------
extern "C" void kernel_launch(void* const* d_in, const int* in_sizes, int n_in,
                              void* d_out, int out_size, void* d_ws, size_t ws_size,
                              hipStream_t stream) {
  const float* x = (const float*)d_in[0];
  const float* context = (const float*)d_in[1];
  const float* g_norm = (const float*)d_in[2];
  const float* null_kv = (const float*)d_in[3];
  const float* Wq = (const float*)d_in[4];
  const float* Wkv = (const float*)d_in[5];
  const float* q_scale = (const float*)d_in[6];
  const float* k_scale = (const float*)d_in[7];
  const float* Wout = (const float*)d_in[8];
  const float* g_out = (const float*)d_in[9];
  float* out = (float*)d_out;

  char* ws = (char*)d_ws;
  u16* xn = (u16*)(ws);                      // 16,777,216 B
  u16* ctxb = (u16*)(ws + 16777216);         // 16,777,216
  u16* wqT = (u16*)(ws + 33554432);          // 2,097,152
  u16* wkvT = (u16*)(ws + 35651584);         // 4,194,304
  u16* woutT = (u16*)(ws + 39845888);        // 2,097,152
  u16* qnb = (u16*)(ws + 41943040);          // 16,777,216
  u16* knb = (u16*)(ws + 58720256);          // 17,825,792
  u16* vtb = (u16*)(ws + 76546048);          // 17,825,792
  u16* vg = (u16*)(ws + 94371840);           // 16,777,216
  float* outg = (float*)(ws + 111149056);    // 33,554,432 -> total 144,703,488
  u16* attn_out = vg;                        // vg fully consumed by v_post

  ln_kernel<true><<<8192, 256, 0, stream>>>(x, g_norm, xn);
  cast_bf16<<<8192, 256, 0, stream>>>(context, ctxb, 2097152);
  transpose_cast<<<dim3(32, 32), 256, 0, stream>>>(Wq, wqT, 1024, 1024);
  transpose_cast<<<dim3(64, 32), 256, 0, stream>>>(Wkv, wkvT, 1024, 2048);
  transpose_cast<<<dim3(32, 32), 256, 0, stream>>>(Wout, woutT, 1024, 1024);
  gemm_bt<2><<<dim3(8, 64), 256, 0, stream>>>(xn, wqT, qnb, 8192, 1024, 1024, q_scale, nullptr);
  gemm_bt<3><<<dim3(16, 64), 256, 0, stream>>>(ctxb, wkvT, knb, 8192, 2048, 1024, k_scale, vg);
  v_post<<<dim3(32, 64), 256, 0, stream>>>(vg, vtb);
  null_tail<<<64, 256, 0, stream>>>(null_kv, k_scale, knb, vtb);
  attn_kernel<<<dim3(32, 64), 256, 0, stream>>>(qnb, knb, vtb, attn_out);
  gemm_bt<0><<<dim3(8, 64), 256, 0, stream>>>(attn_out, woutT, outg, 8192, 1024, 1024, nullptr, nullptr);
  ln_kernel<false><<<8192, 256, 0, stream>>>(outg, g_out, out);
}

// Round 10
// 414.568 us; speedup vs baseline: 1.0365x; 1.0365x over previous
//
#include <hip/hip_runtime.h>

// Problem constants
#define BATCH 4
#define NSEQ 2048
#define MSEQ 2048
#define DIM 1024
#define HEADS 16
#define DHEAD 64
#define INNER 1024
#define KVLEN 2049          // null token + MSEQ
#define KVPAD 2176          // 17 * 128

typedef unsigned short u16;
typedef unsigned int u32;
typedef __bf16 bf16x8 __attribute__((ext_vector_type(8)));
typedef float f32x4 __attribute__((ext_vector_type(4)));

__device__ inline u16 f2bf(float f) {
  u32 u = __builtin_bit_cast(u32, f);
  u = (u + 0x7fffu + ((u >> 16) & 1u)) >> 16;
  return (u16)u;
}
__device__ inline float bf2f(u16 x) {
  return __builtin_bit_cast(float, (u32)x << 16);
}
// packed bf16 convert: lo -> D[15:0], hi -> D[31:16] (RNE)
__device__ inline u32 pk_bf16(float lo, float hi) {
  u32 r;
  asm("v_cvt_pk_bf16_f32 %0, %1, %2" : "=v"(r) : "v"(lo), "v"(hi));
  return r;
}

__device__ __forceinline__ void gld_lds16(const void* g, void* l) {
  __builtin_amdgcn_global_load_lds(
      (const __attribute__((address_space(1))) void*)g,
      (__attribute__((address_space(3))) void*)l, 16, 0, 0);
}

// ---------------- LayerNorm (row of 1024), output bf16 or fp32 ----------------
template <bool OUT_BF16>
__global__ __launch_bounds__(256) void ln_kernel(const float* __restrict__ x,
                                                 const float* __restrict__ g,
                                                 void* __restrict__ out) {
  const int row = blockIdx.x;
  const int t = threadIdx.x;
  const float4 v = ((const float4*)(x + (size_t)row * 1024))[t];
  float sum = v.x + v.y + v.z + v.w;
  float sq = v.x * v.x + v.y * v.y + v.z * v.z + v.w * v.w;
  for (int m = 1; m < 64; m <<= 1) {
    sum += __shfl_xor(sum, m, 64);
    sq += __shfl_xor(sq, m, 64);
  }
  __shared__ float red[8];
  const int w = t >> 6, l = t & 63;
  if (l == 0) { red[w] = sum; red[4 + w] = sq; }
  __syncthreads();
  sum = red[0] + red[1] + red[2] + red[3];
  sq = red[4] + red[5] + red[6] + red[7];
  const float mean = sum * (1.0f / 1024.0f);
  const float var = sq * (1.0f / 1024.0f) - mean * mean;
  const float rstd = rsqrtf(var + 1e-5f);
  const float4 gv = ((const float4*)g)[t];
  float o0 = (v.x - mean) * rstd * gv.x;
  float o1 = (v.y - mean) * rstd * gv.y;
  float o2 = (v.z - mean) * rstd * gv.z;
  float o3 = (v.w - mean) * rstd * gv.w;
  if (OUT_BF16) {
    ushort4 ov;
    ov.x = f2bf(o0); ov.y = f2bf(o1); ov.z = f2bf(o2); ov.w = f2bf(o3);
    ((ushort4*)((u16*)out + (size_t)row * 1024))[t] = ov;
  } else {
    float4 ov;
    ov.x = o0; ov.y = o1; ov.z = o2; ov.w = o3;
    ((float4*)((float*)out + (size_t)row * 1024))[t] = ov;
  }
}

// ---------------- fp32 -> bf16 cast (vectorized by 4) ----------------
__global__ __launch_bounds__(256) void cast_bf16(const float* __restrict__ in,
                                                 u16* __restrict__ out, int n4) {
  int i = blockIdx.x * 256 + threadIdx.x;
  if (i < n4) {
    float4 v = ((const float4*)in)[i];
    ushort4 o;
    o.x = f2bf(v.x); o.y = f2bf(v.y); o.z = f2bf(v.z); o.w = f2bf(v.w);
    ((ushort4*)out)[i] = o;
  }
}

// ---------------- W[K][N] fp32 -> WT[N][K] bf16 (tiled transpose) ----------------
__global__ __launch_bounds__(256) void transpose_cast(const float* __restrict__ W,
                                                      u16* __restrict__ WT, int K, int N) {
  __shared__ float tile[32][33];
  const int tx = threadIdx.x & 31, ty = threadIdx.x >> 5;  // ty 0..7
  const int k0 = blockIdx.y * 32, n0 = blockIdx.x * 32;
  for (int r = ty; r < 32; r += 8) tile[r][tx] = W[(size_t)(k0 + r) * N + n0 + tx];
  __syncthreads();
  for (int r = ty; r < 32; r += 8) WT[(size_t)(n0 + r) * K + k0 + tx] = f2bf(tile[tx][r]);
}

// ---------------- bf16 GEMM: C = A[M][K] @ Bt[N][K]^T ----------------
// MODE 0: fp32 C row-major. MODE 1: bf16 C row-major.
// MODE 2: fused q_post -> l2norm(head)*scale*8, write qn[b,h,n,64].
// MODE 3: fused kv post -> heads 0..15: l2norm*k_scale -> kn[b,h,m+1,64];
//                          heads 16..31: plain bf16 -> aux[row][ (h-16)*64+d ].
template <int MODE>
__global__ __launch_bounds__(256) void gemm_bt(const u16* __restrict__ A,
                                               const u16* __restrict__ Bt,
                                               void* __restrict__ Cv,
                                               int M, int N, int K,
                                               const float* __restrict__ scale,
                                               u16* __restrict__ aux) {
  __shared__ __align__(16) u16 As[128 * 32];
  __shared__ __align__(16) u16 Bs[128 * 32];
  const int t = threadIdx.x;
  const int w = t >> 6, l = t & 63, l15 = l & 15, lq = l >> 4;
  const int m0 = blockIdx.y * 128, n0 = blockIdx.x * 128;
  const int wm = (w >> 1) * 64, wn = (w & 1) * 64;
  const int lr = l >> 2;           // 0..15 row-within-chunk
  const int lo = (l & 3) * 8;      // u16 offset within row: 0,8,16,24
  f32x4 acc[4][4] = {};
  for (int k0 = 0; k0 < K; k0 += 32) {
#pragma unroll
    for (int it = 0; it < 2; it++) {
      const int row = (w * 2 + it) * 16 + lr;   // 0..127
      gld_lds16(&A[(size_t)(m0 + row) * K + k0 + lo], &As[row * 32 + lo]);
      gld_lds16(&Bt[(size_t)(n0 + row) * K + k0 + lo], &Bs[row * 32 + lo]);
    }
    __syncthreads();
    bf16x8 af[4], bfr[4];
#pragma unroll
    for (int i = 0; i < 4; i++) af[i] = *(bf16x8*)&As[(wm + i * 16 + l15) * 32 + lq * 8];
#pragma unroll
    for (int j = 0; j < 4; j++) bfr[j] = *(bf16x8*)&Bs[(wn + j * 16 + l15) * 32 + lq * 8];
#pragma unroll
    for (int i = 0; i < 4; i++)
#pragma unroll
      for (int j = 0; j < 4; j++)
        acc[i][j] = __builtin_amdgcn_mfma_f32_16x16x32_bf16(af[i], bfr[j], acc[i][j], 0, 0, 0);
    __syncthreads();
  }

  if (MODE <= 1) {
#pragma unroll
    for (int i = 0; i < 4; i++)
#pragma unroll
      for (int j = 0; j < 4; j++)
#pragma unroll
        for (int r = 0; r < 4; r++) {
          const size_t off =
              (size_t)(m0 + wm + i * 16 + lq * 4 + r) * N + n0 + wn + j * 16 + l15;
          if (MODE == 1) ((u16*)Cv)[off] = f2bf(acc[i][j][r]);
          else ((float*)Cv)[off] = acc[i][j][r];
        }
    return;
  }

  const int head = (n0 + wn) >> 6;  // wave-uniform
  if (MODE == 3 && head >= 16) {
    // V columns: plain bf16 into compact aux[row][ (head-16)*64 + d ]
#pragma unroll
    for (int i = 0; i < 4; i++)
#pragma unroll
      for (int j = 0; j < 4; j++)
#pragma unroll
        for (int r = 0; r < 4; r++) {
          const int row = m0 + wm + i * 16 + lq * 4 + r;
          aux[(size_t)row * 1024 + (head - 16) * 64 + j * 16 + l15] = f2bf(acc[i][j][r]);
        }
    return;
  }
  // l2norm over the 64-col head + scale (q: *8)
  float sc[4];
#pragma unroll
  for (int j = 0; j < 4; j++) sc[j] = scale[j * 16 + l15];
  const float mul = (MODE == 2) ? 8.0f : 1.0f;
  u16* outp = (u16*)Cv;
#pragma unroll
  for (int i = 0; i < 4; i++)
#pragma unroll
    for (int r = 0; r < 4; r++) {
      float ss = 0.f;
#pragma unroll
      for (int j = 0; j < 4; j++) ss = fmaf(acc[i][j][r], acc[i][j][r], ss);
#pragma unroll
      for (int m = 1; m < 16; m <<= 1) ss += __shfl_xor(ss, m, 64);
      const float inv = mul / fmaxf(sqrtf(ss), 1e-12f);
      const int row = m0 + wm + i * 16 + lq * 4 + r;
      const int b = row >> 11, n = row & 2047;
      const size_t base = (MODE == 2)
          ? (((size_t)b * 16 + head) * 2048 + n) * 64
          : (((size_t)b * 16 + head) * (size_t)KVPAD + n + 1) * 64;
#pragma unroll
      for (int j = 0; j < 4; j++)
        outp[base + j * 16 + l15] = f2bf(acc[i][j][r] * inv * sc[j]);
    }
}

// ---------------- v post: transpose vg[row][h*64+d] -> vt[b,h,64,KVPAD] ----------------
// The KV (column) index is stored k-PERMUTED within each 128-aligned block
// by the bit-permutation matching the in-register P fragments of attn_kernel:
//   forward g(slot): [s6 s5 s4 s3 s2 s1 s0] -> kv-local [s6 s5 s2 s4 s3 s1 s0]
//   inverse slot(a) = (a & 0x63) | ((a & 0x10) >> 2) | ((a & 0x0C) << 1)
// slot() keeps bits 0,1,5,6 fixed -> it maps every 64-aligned block onto
// itself (required by attn's KVBLK=64 tiling). slot(0)=0, so null_tail
// (null token slot 0, tail zeroing 2049..2175) is unchanged.
__global__ __launch_bounds__(256) void v_post(const u16* __restrict__ vg,
                                              u16* __restrict__ vt) {
  __shared__ u16 tile[64][68];
  const int bh = blockIdx.y, mt = blockIdx.x;
  const int tx = threadIdx.x & 63, ty = threadIdx.x >> 6;
  const int b = bh >> 4, h = bh & 15;
  const int m0 = mt * 64;
  for (int r = ty; r < 64; r += 4)
    tile[tx][r] = vg[(size_t)(b * 2048 + m0 + r) * 1024 + h * 64 + tx];
  __syncthreads();
  const int abs_ = 1 + m0 + tx;
  const int a = abs_ & 127;
  const int slot = (abs_ & ~127) | (a & 0x63) | ((a & 0x10) >> 2) | ((a & 0x0C) << 1);
  for (int d = ty; d < 64; d += 4)
    vt[((size_t)bh * 64 + d) * KVPAD + slot] = tile[d][tx];
}

// ---------------- null token + tail zeroing (256-thread version, R5-verified) ----------------
__global__ __launch_bounds__(256) void null_tail(const float* __restrict__ null_kv,
                                                 const float* __restrict__ k_scale,
                                                 u16* __restrict__ kn, u16* __restrict__ vt) {
  const int bh = blockIdx.x, t = threadIdx.x;
  const int d = t & 63, seg = t >> 6;  // seg 0..3
  if (seg == 0) {  // one full wave: null token (needs 64-lane reduction)
    float nk = null_kv[d];
    float nv = null_kv[64 + d];
    float ss = nk * nk;
    for (int m = 1; m < 64; m <<= 1) ss += __shfl_xor(ss, m, 64);
    float inv = 1.0f / fmaxf(sqrtf(ss), 1e-12f);
    kn[((size_t)bh * KVPAD) * 64 + d] = f2bf(nk * inv * k_scale[d]);
    vt[((size_t)bh * 64 + d) * KVPAD] = f2bf(nv);  // slot(0) == 0
  }
  for (int m = KVLEN + seg; m < KVPAD; m += 4) kn[((size_t)bh * KVPAD + m) * 64 + d] = 0;
  u16* vrow = vt + ((size_t)bh * 64 + d) * KVPAD;
  for (int m = KVLEN + seg; m < KVPAD; m += 4) vrow[m] = 0;
}

// ---------------- flash attention, fixed-max softmax ----------------
// |sim| <= 8 by Cauchy-Schwarz (l2norm'd q,k; scales==1; SCALE=8) -> static max 8.
// Structure (R7/R8-banked): SWAPPED QK^T — mfma(K_frag, Q_frag) gives D = S^T;
// lane (l15,lq) reg r of tile j holds S[q=l15][kv-local=j*16+lq*4+r]. P stays
// in registers (v_cvt_pk_bf16_f32 -> pa frags); V rows g-permuted (v_post);
// lsum on the MFMA pipe via mfma(pa, ones). Staging: global_load_lds, linear
// LDS, source-side bank swizzle (R9's KVBLK=64 swizzle measured conflict-FREE).
// R9 post-mortem: KVBLK=64 + launch_bounds(256,8) forced VGPR to 32 ->
// SCRATCH SPILLS (WRITE_SIZE 16K->53K, hbm_bytes 2x, MfmaUtil 38->25,
// 139us despite Occ 74%). R10: same kernel, launch_bounds(256,6) -> VGPR cap
// 85, no spill expected; LDS 16KB allows up to 10 blocks/CU, VGPR gives 6-8.
// This isolates the occupancy theory from the spill confound.
// R5 post-mortem: direct-global fragments 3.6x WORSE. R2/R3: 32-q-rows/wave
// variant fails correctness (unlocalized); don't re-attempt without bisection.
__global__ __launch_bounds__(256, 6) void attn_kernel(const u16* __restrict__ qn,
                                                      const u16* __restrict__ kn,
                                                      const u16* __restrict__ vt,
                                                      u16* __restrict__ aout) {
  __shared__ __align__(16) u16 Ks[64 * 64];  // K tile (linear, src-swizzled)
  __shared__ __align__(16) u16 Vs[64 * 64];  // V^T tile (linear, src-swizzled, g-permuted kv)
  const int qt = blockIdx.x, bh = blockIdx.y;
  const int b = bh >> 4, h = bh & 15;
  const int t = threadIdx.x, w = t >> 6, l = t & 63, l15 = l & 15, lq = l >> 4;

  // Q fragments straight from global (loop-invariant); used as MFMA B-operand
  bf16x8 aqf[2];
  {
    const u16* qrow = qn + ((size_t)bh * 2048 + qt * 64 + w * 16 + l15) * 64 + lq * 8;
    aqf[0] = *(const bf16x8*)(qrow);
    aqf[1] = *(const bf16x8*)(qrow + 32);
  }

  // constant ones vector (bf16 1.0 = 0x3F80) for the lsum MFMA
  const uint4 onesu = {0x3F803F80u, 0x3F803F80u, 0x3F803F80u, 0x3F803F80u};
  const bf16x8 vones = __builtin_bit_cast(bf16x8, onesu);

  // swizzled fragment-read slot offsets (u16): slot' = (i*4+lq) ^ (l15&7), i=0..1
  int so[2];
#pragma unroll
  for (int i = 0; i < 2; i++) so[i] = ((i * 4 + lq) ^ (l15 & 7)) * 8;

  // staging: per-lane swizzled GLOBAL source, linear LDS dest (base + lane*16).
  // Both tiles are 64 rows x 64 u16 = 8 KB: 2 gld_lds rounds of 32 rows each.
  // Round i, thread t: row = i*32 + w*8 + (l>>3); 16B slot = (l&7) ^ (l>>3)
  // (row&7 == l>>3 since w*8, i*32 are 0 mod 8).
  const u16* kn_b = kn + (size_t)bh * KVPAD * 64;
  const u16* vt_b = vt + (size_t)bh * 64 * KVPAD;
  const u16* ksrc[2];
  const u16* vsrc[2];
#pragma unroll
  for (int i = 0; i < 2; i++) {
    const int row = i * 32 + w * 8 + (l >> 3);
    const int sl = (l & 7) ^ (l >> 3);
    ksrc[i] = kn_b + row * 64 + sl * 8;
    vsrc[i] = vt_b + (size_t)row * KVPAD + sl * 8;
  }
  u16* kdst = &Ks[w * 512 + l * 8];
  u16* vdst = &Vs[w * 512 + l * 8];

  f32x4 O[4] = {};
  f32x4 lsacc = {};  // lsum[q=lq*4+r] in reg r (all l15 identical)
  const float LOG2E = 1.44269504f;
  const float MBIAS = -8.0f * 1.44269504f;  // exp(s-8) = 2^(s*log2e + MBIAS)

  for (int kt = 0; kt < 33; kt++) {  // 33 of 34 tiles: tile 33 is all padding
    // ---- stage K (64x64) and V^T (64x64) via global_load_lds, src-swizzled ----
#pragma unroll
    for (int i = 0; i < 2; i++) {
      gld_lds16(ksrc[i] + kt * 4096, kdst + i * 2048);
      gld_lds16(vsrc[i] + kt * 64, vdst + i * 2048);
    }
    __syncthreads();  // compiler drains vmcnt before s_barrier

    // ---- S^T = K Q^T (swapped): St[j] lane(l15,lq) reg r = S[q=l15][j*16+lq*4+r] ----
    f32x4 St[4] = {};
    __builtin_amdgcn_s_setprio(1);
#pragma unroll
    for (int ks = 0; ks < 2; ks++)
#pragma unroll
      for (int j = 0; j < 4; j++) {
        bf16x8 ak = *(bf16x8*)&Ks[(j * 16 + l15) * 64 + so[ks]];
        St[j] = __builtin_amdgcn_mfma_f32_16x16x32_bf16(ak, aqf[ks], St[j], 0, 0, 0);
      }
    __builtin_amdgcn_s_setprio(0);

    // ---- P = exp(S - 8) in registers; mask pass uniform-branched; pack pa ----
    float p[4][4];
#pragma unroll
    for (int j = 0; j < 4; j++)
#pragma unroll
      for (int r = 0; r < 4; r++)
        p[j][r] = __builtin_amdgcn_exp2f(fmaf(St[j][r], LOG2E, MBIAS));
    if (kt == 32) {  // uniform branch: only kv-local 0 (global 2048) is valid
#pragma unroll
      for (int j = 0; j < 4; j++)
#pragma unroll
        for (int r = 0; r < 4; r++)
          if ((j | r) != 0) p[j][r] = 0.f;        // compile-time for j|r != 0
      if (lq != 0) p[0][0] = 0.f;                 // lane-dependent only here
    }
    bf16x8 pa[2];
#pragma unroll
    for (int m = 0; m < 2; m++) {
      uint4 pw;
      pw.x = pk_bf16(p[2 * m][0], p[2 * m][1]);
      pw.y = pk_bf16(p[2 * m][2], p[2 * m][3]);
      pw.z = pk_bf16(p[2 * m + 1][0], p[2 * m + 1][1]);
      pw.w = pk_bf16(p[2 * m + 1][2], p[2 * m + 1][3]);
      pa[m] = __builtin_bit_cast(bf16x8, pw);
    }

    // ---- O += P V; lsum += P @ ones (MFMA pipe, no VALU) ----
    __builtin_amdgcn_s_setprio(1);
#pragma unroll
    for (int m = 0; m < 2; m++) {
      lsacc = __builtin_amdgcn_mfma_f32_16x16x32_bf16(pa[m], vones, lsacc, 0, 0, 0);
#pragma unroll
      for (int nt = 0; nt < 4; nt++) {
        bf16x8 bv = *(bf16x8*)&Vs[(nt * 16 + l15) * 64 + so[m]];
        O[nt] = __builtin_amdgcn_mfma_f32_16x16x32_bf16(pa[m], bv, O[nt], 0, 0, 0);
      }
    }
    __builtin_amdgcn_s_setprio(0);
    __syncthreads();  // K/V reads done before next staging overwrites
  }

  // ---- normalize + store (lsacc[r] already in O's register layout) ----
  float inv[4];
#pragma unroll
  for (int r = 0; r < 4; r++) inv[r] = 1.0f / lsacc[r];
#pragma unroll
  for (int nt = 0; nt < 4; nt++)
#pragma unroll
    for (int r = 0; r < 4; r++) {
      int row = qt * 64 + w * 16 + lq * 4 + r;
      int col = h * 64 + nt * 16 + l15;
      float val = O[nt][r] * inv[r];
      aout[((size_t)b * 2048 + row) * 1024 + col] = f2bf(val);
    }
}

// ---------------- host launch ----------------
extern "C" void kernel_launch(void* const* d_in, const int* in_sizes, int n_in,
                              void* d_out, int out_size, void* d_ws, size_t ws_size,
                              hipStream_t stream) {
  const float* x = (const float*)d_in[0];
  const float* context = (const float*)d_in[1];
  const float* g_norm = (const float*)d_in[2];
  const float* null_kv = (const float*)d_in[3];
  const float* Wq = (const float*)d_in[4];
  const float* Wkv = (const float*)d_in[5];
  const float* q_scale = (const float*)d_in[6];
  const float* k_scale = (const float*)d_in[7];
  const float* Wout = (const float*)d_in[8];
  const float* g_out = (const float*)d_in[9];
  float* out = (float*)d_out;

  char* ws = (char*)d_ws;
  u16* xn = (u16*)(ws);                      // 16,777,216 B
  u16* ctxb = (u16*)(ws + 16777216);         // 16,777,216
  u16* wqT = (u16*)(ws + 33554432);          // 2,097,152
  u16* wkvT = (u16*)(ws + 35651584);         // 4,194,304
  u16* woutT = (u16*)(ws + 39845888);        // 2,097,152
  u16* qnb = (u16*)(ws + 41943040);          // 16,777,216
  u16* knb = (u16*)(ws + 58720256);          // 17,825,792
  u16* vtb = (u16*)(ws + 76546048);          // 17,825,792
  u16* vg = (u16*)(ws + 94371840);           // 16,777,216
  float* outg = (float*)(ws + 111149056);    // 33,554,432 -> total 144,703,488
  u16* attn_out = vg;                        // vg fully consumed by v_post

  ln_kernel<true><<<8192, 256, 0, stream>>>(x, g_norm, xn);
  cast_bf16<<<8192, 256, 0, stream>>>(context, ctxb, 2097152);
  transpose_cast<<<dim3(32, 32), 256, 0, stream>>>(Wq, wqT, 1024, 1024);
  transpose_cast<<<dim3(64, 32), 256, 0, stream>>>(Wkv, wkvT, 1024, 2048);
  transpose_cast<<<dim3(32, 32), 256, 0, stream>>>(Wout, woutT, 1024, 1024);
  gemm_bt<2><<<dim3(8, 64), 256, 0, stream>>>(xn, wqT, qnb, 8192, 1024, 1024, q_scale, nullptr);
  gemm_bt<3><<<dim3(16, 64), 256, 0, stream>>>(ctxb, wkvT, knb, 8192, 2048, 1024, k_scale, vg);
  v_post<<<dim3(32, 64), 256, 0, stream>>>(vg, vtb);
  null_tail<<<64, 256, 0, stream>>>(null_kv, k_scale, knb, vtb);
  attn_kernel<<<dim3(32, 64), 256, 0, stream>>>(qnb, knb, vtb, attn_out);
  gemm_bt<0><<<dim3(8, 64), 256, 0, stream>>>(attn_out, woutT, outg, 8192, 1024, 1024, nullptr, nullptr);
  ln_kernel<false><<<8192, 256, 0, stream>>>(outg, g_out, out);
}

// Round 11
// 395.027 us; speedup vs baseline: 1.0877x; 1.0495x over previous
//
#include <hip/hip_runtime.h>

// Problem constants
#define BATCH 4
#define NSEQ 2048
#define MSEQ 2048
#define DIM 1024
#define HEADS 16
#define DHEAD 64
#define INNER 1024
#define KVLEN 2049          // null token + MSEQ
#define KVPAD 2176          // 17 * 128

typedef unsigned short u16;
typedef unsigned int u32;
typedef __bf16 bf16x8 __attribute__((ext_vector_type(8)));
typedef float f32x4 __attribute__((ext_vector_type(4)));

__device__ inline u16 f2bf(float f) {
  u32 u = __builtin_bit_cast(u32, f);
  u = (u + 0x7fffu + ((u >> 16) & 1u)) >> 16;
  return (u16)u;
}
__device__ inline float bf2f(u16 x) {
  return __builtin_bit_cast(float, (u32)x << 16);
}
// packed bf16 convert: lo -> D[15:0], hi -> D[31:16] (RNE)
__device__ inline u32 pk_bf16(float lo, float hi) {
  u32 r;
  asm("v_cvt_pk_bf16_f32 %0, %1, %2" : "=v"(r) : "v"(lo), "v"(hi));
  return r;
}

__device__ __forceinline__ void gld_lds16(const void* g, void* l) {
  __builtin_amdgcn_global_load_lds(
      (const __attribute__((address_space(1))) void*)g,
      (__attribute__((address_space(3))) void*)l, 16, 0, 0);
}

// ---------------- LayerNorm (row of 1024), output bf16 or fp32 ----------------
template <bool OUT_BF16>
__global__ __launch_bounds__(256) void ln_kernel(const float* __restrict__ x,
                                                 const float* __restrict__ g,
                                                 void* __restrict__ out) {
  const int row = blockIdx.x;
  const int t = threadIdx.x;
  const float4 v = ((const float4*)(x + (size_t)row * 1024))[t];
  float sum = v.x + v.y + v.z + v.w;
  float sq = v.x * v.x + v.y * v.y + v.z * v.z + v.w * v.w;
  for (int m = 1; m < 64; m <<= 1) {
    sum += __shfl_xor(sum, m, 64);
    sq += __shfl_xor(sq, m, 64);
  }
  __shared__ float red[8];
  const int w = t >> 6, l = t & 63;
  if (l == 0) { red[w] = sum; red[4 + w] = sq; }
  __syncthreads();
  sum = red[0] + red[1] + red[2] + red[3];
  sq = red[4] + red[5] + red[6] + red[7];
  const float mean = sum * (1.0f / 1024.0f);
  const float var = sq * (1.0f / 1024.0f) - mean * mean;
  const float rstd = rsqrtf(var + 1e-5f);
  const float4 gv = ((const float4*)g)[t];
  float o0 = (v.x - mean) * rstd * gv.x;
  float o1 = (v.y - mean) * rstd * gv.y;
  float o2 = (v.z - mean) * rstd * gv.z;
  float o3 = (v.w - mean) * rstd * gv.w;
  if (OUT_BF16) {
    ushort4 ov;
    ov.x = f2bf(o0); ov.y = f2bf(o1); ov.z = f2bf(o2); ov.w = f2bf(o3);
    ((ushort4*)((u16*)out + (size_t)row * 1024))[t] = ov;
  } else {
    float4 ov;
    ov.x = o0; ov.y = o1; ov.z = o2; ov.w = o3;
    ((float4*)((float*)out + (size_t)row * 1024))[t] = ov;
  }
}

// ---------------- fp32 -> bf16 cast (vectorized by 4) ----------------
__global__ __launch_bounds__(256) void cast_bf16(const float* __restrict__ in,
                                                 u16* __restrict__ out, int n4) {
  int i = blockIdx.x * 256 + threadIdx.x;
  if (i < n4) {
    float4 v = ((const float4*)in)[i];
    ushort4 o;
    o.x = f2bf(v.x); o.y = f2bf(v.y); o.z = f2bf(v.z); o.w = f2bf(v.w);
    ((ushort4*)out)[i] = o;
  }
}

// ---------------- W[K][N] fp32 -> WT[N][K] bf16 (tiled transpose) ----------------
__global__ __launch_bounds__(256) void transpose_cast(const float* __restrict__ W,
                                                      u16* __restrict__ WT, int K, int N) {
  __shared__ float tile[32][33];
  const int tx = threadIdx.x & 31, ty = threadIdx.x >> 5;  // ty 0..7
  const int k0 = blockIdx.y * 32, n0 = blockIdx.x * 32;
  for (int r = ty; r < 32; r += 8) tile[r][tx] = W[(size_t)(k0 + r) * N + n0 + tx];
  __syncthreads();
  for (int r = ty; r < 32; r += 8) WT[(size_t)(n0 + r) * K + k0 + tx] = f2bf(tile[tx][r]);
}

// ---------------- bf16 GEMM: C = A[M][K] @ Bt[N][K]^T ----------------
// MODE 0: fp32 C row-major. MODE 1: bf16 C row-major.
// MODE 2: fused q_post -> l2norm(head)*scale*8, write qn[b,h,n,64].
// MODE 3: fused kv post -> heads 0..15: l2norm*k_scale -> kn[b,h,m+1,64];
//                          heads 16..31: plain bf16 -> aux[row][ (h-16)*64+d ].
template <int MODE>
__global__ __launch_bounds__(256) void gemm_bt(const u16* __restrict__ A,
                                               const u16* __restrict__ Bt,
                                               void* __restrict__ Cv,
                                               int M, int N, int K,
                                               const float* __restrict__ scale,
                                               u16* __restrict__ aux) {
  __shared__ __align__(16) u16 As[128 * 32];
  __shared__ __align__(16) u16 Bs[128 * 32];
  const int t = threadIdx.x;
  const int w = t >> 6, l = t & 63, l15 = l & 15, lq = l >> 4;
  const int m0 = blockIdx.y * 128, n0 = blockIdx.x * 128;
  const int wm = (w >> 1) * 64, wn = (w & 1) * 64;
  const int lr = l >> 2;           // 0..15 row-within-chunk
  const int lo = (l & 3) * 8;      // u16 offset within row: 0,8,16,24
  f32x4 acc[4][4] = {};
  for (int k0 = 0; k0 < K; k0 += 32) {
#pragma unroll
    for (int it = 0; it < 2; it++) {
      const int row = (w * 2 + it) * 16 + lr;   // 0..127
      gld_lds16(&A[(size_t)(m0 + row) * K + k0 + lo], &As[row * 32 + lo]);
      gld_lds16(&Bt[(size_t)(n0 + row) * K + k0 + lo], &Bs[row * 32 + lo]);
    }
    __syncthreads();
    bf16x8 af[4], bfr[4];
#pragma unroll
    for (int i = 0; i < 4; i++) af[i] = *(bf16x8*)&As[(wm + i * 16 + l15) * 32 + lq * 8];
#pragma unroll
    for (int j = 0; j < 4; j++) bfr[j] = *(bf16x8*)&Bs[(wn + j * 16 + l15) * 32 + lq * 8];
#pragma unroll
    for (int i = 0; i < 4; i++)
#pragma unroll
      for (int j = 0; j < 4; j++)
        acc[i][j] = __builtin_amdgcn_mfma_f32_16x16x32_bf16(af[i], bfr[j], acc[i][j], 0, 0, 0);
    __syncthreads();
  }

  if (MODE <= 1) {
#pragma unroll
    for (int i = 0; i < 4; i++)
#pragma unroll
      for (int j = 0; j < 4; j++)
#pragma unroll
        for (int r = 0; r < 4; r++) {
          const size_t off =
              (size_t)(m0 + wm + i * 16 + lq * 4 + r) * N + n0 + wn + j * 16 + l15;
          if (MODE == 1) ((u16*)Cv)[off] = f2bf(acc[i][j][r]);
          else ((float*)Cv)[off] = acc[i][j][r];
        }
    return;
  }

  const int head = (n0 + wn) >> 6;  // wave-uniform
  if (MODE == 3 && head >= 16) {
    // V columns: plain bf16 into compact aux[row][ (head-16)*64 + d ]
#pragma unroll
    for (int i = 0; i < 4; i++)
#pragma unroll
      for (int j = 0; j < 4; j++)
#pragma unroll
        for (int r = 0; r < 4; r++) {
          const int row = m0 + wm + i * 16 + lq * 4 + r;
          aux[(size_t)row * 1024 + (head - 16) * 64 + j * 16 + l15] = f2bf(acc[i][j][r]);
        }
    return;
  }
  // l2norm over the 64-col head + scale (q: *8)
  float sc[4];
#pragma unroll
  for (int j = 0; j < 4; j++) sc[j] = scale[j * 16 + l15];
  const float mul = (MODE == 2) ? 8.0f : 1.0f;
  u16* outp = (u16*)Cv;
#pragma unroll
  for (int i = 0; i < 4; i++)
#pragma unroll
    for (int r = 0; r < 4; r++) {
      float ss = 0.f;
#pragma unroll
      for (int j = 0; j < 4; j++) ss = fmaf(acc[i][j][r], acc[i][j][r], ss);
#pragma unroll
      for (int m = 1; m < 16; m <<= 1) ss += __shfl_xor(ss, m, 64);
      const float inv = mul / fmaxf(sqrtf(ss), 1e-12f);
      const int row = m0 + wm + i * 16 + lq * 4 + r;
      const int b = row >> 11, n = row & 2047;
      const size_t base = (MODE == 2)
          ? (((size_t)b * 16 + head) * 2048 + n) * 64
          : (((size_t)b * 16 + head) * (size_t)KVPAD + n + 1) * 64;
#pragma unroll
      for (int j = 0; j < 4; j++)
        outp[base + j * 16 + l15] = f2bf(acc[i][j][r] * inv * sc[j]);
    }
}

// ---------------- v post: transpose vg[row][h*64+d] -> vt[b,h,64,KVPAD] ----------------
// The KV (column) index is stored k-PERMUTED within each 128-aligned block
// by the bit-permutation matching the in-register P fragments of attn_kernel:
//   forward g(slot): [s6 s5 s4 s3 s2 s1 s0] -> kv-local [s6 s5 s2 s4 s3 s1 s0]
//   inverse slot(a) = (a & 0x63) | ((a & 0x10) >> 2) | ((a & 0x0C) << 1)
// slot() keeps bits 0,1,5,6 fixed -> it maps every 64-aligned block onto
// itself (required by attn's KVBLK=64 tiling). slot(0)=0, so null_tail
// (null token slot 0, tail zeroing 2049..2175) is unchanged.
__global__ __launch_bounds__(256) void v_post(const u16* __restrict__ vg,
                                              u16* __restrict__ vt) {
  __shared__ u16 tile[64][68];
  const int bh = blockIdx.y, mt = blockIdx.x;
  const int tx = threadIdx.x & 63, ty = threadIdx.x >> 6;
  const int b = bh >> 4, h = bh & 15;
  const int m0 = mt * 64;
  for (int r = ty; r < 64; r += 4)
    tile[tx][r] = vg[(size_t)(b * 2048 + m0 + r) * 1024 + h * 64 + tx];
  __syncthreads();
  const int abs_ = 1 + m0 + tx;
  const int a = abs_ & 127;
  const int slot = (abs_ & ~127) | (a & 0x63) | ((a & 0x10) >> 2) | ((a & 0x0C) << 1);
  for (int d = ty; d < 64; d += 4)
    vt[((size_t)bh * 64 + d) * KVPAD + slot] = tile[d][tx];
}

// ---------------- null token + tail zeroing (256-thread version, R5-verified) ----------------
__global__ __launch_bounds__(256) void null_tail(const float* __restrict__ null_kv,
                                                 const float* __restrict__ k_scale,
                                                 u16* __restrict__ kn, u16* __restrict__ vt) {
  const int bh = blockIdx.x, t = threadIdx.x;
  const int d = t & 63, seg = t >> 6;  // seg 0..3
  if (seg == 0) {  // one full wave: null token (needs 64-lane reduction)
    float nk = null_kv[d];
    float nv = null_kv[64 + d];
    float ss = nk * nk;
    for (int m = 1; m < 64; m <<= 1) ss += __shfl_xor(ss, m, 64);
    float inv = 1.0f / fmaxf(sqrtf(ss), 1e-12f);
    kn[((size_t)bh * KVPAD) * 64 + d] = f2bf(nk * inv * k_scale[d]);
    vt[((size_t)bh * 64 + d) * KVPAD] = f2bf(nv);  // slot(0) == 0
  }
  for (int m = KVLEN + seg; m < KVPAD; m += 4) kn[((size_t)bh * KVPAD + m) * 64 + d] = 0;
  u16* vrow = vt + ((size_t)bh * 64 + d) * KVPAD;
  for (int m = KVLEN + seg; m < KVPAD; m += 4) vrow[m] = 0;
}

// ---------------- flash attention, fixed-max softmax ----------------
// |sim| <= 8 by Cauchy-Schwarz (l2norm'd q,k; scales==1; SCALE=8) -> static max 8.
// Structure (R7/R8-banked): SWAPPED QK^T — mfma(K_frag, Q_frag) gives D = S^T;
// lane (l15,lq) reg r of tile j holds S[q][kv-local=j*16+lq*4+r]. P stays in
// registers (v_cvt_pk_bf16_f32 -> pa frags); V rows g-permuted (v_post); lsum
// on the MFMA pipe via mfma(pa, ones). Staging: global_load_lds, linear LDS,
// source-side bank swizzle (conflict-free, measured 0 in R9/R10).
// R11 delta: 32 q-rows/WAVE (2 sub-tiles i=0,1). R10 counters (Occ 47% with
// dur unchanged vs R8's 36%) falsified the occupancy theory; arithmetic says
// LDS-read issue is the floor (16 b128/wave/kt x 33 x 32 waves/CU x ~12cyc
// ~= 84us of the 94.6). Each ak/bv read now feeds 2 MFMAs (both q sub-tiles)
// -> block covers 128 q rows, grid.x 32->16, TOTAL LDS READS HALVE. The
// R2/R3 failure mechanism (P-LDS aliasing) no longer exists — this change is
// pure register duplication: i=0 instance IS the R10 kernel; i=1 differs only
// by +16 in Q-row base and output row. launch_bounds(256,4) -> 128 VGPR cap
// (R9 lesson: spill shows as WRITE_SIZE jump -> falsifier).
// R5 post-mortem: direct-global fragments 3.6x WORSE.
__global__ __launch_bounds__(256, 4) void attn_kernel(const u16* __restrict__ qn,
                                                      const u16* __restrict__ kn,
                                                      const u16* __restrict__ vt,
                                                      u16* __restrict__ aout) {
  __shared__ __align__(16) u16 Ks[64 * 64];  // K tile (linear, src-swizzled)
  __shared__ __align__(16) u16 Vs[64 * 64];  // V^T tile (linear, src-swizzled, g-permuted kv)
  const int qt = blockIdx.x, bh = blockIdx.y;
  const int b = bh >> 4, h = bh & 15;
  const int t = threadIdx.x, w = t >> 6, l = t & 63, l15 = l & 15, lq = l >> 4;

  // Q fragments (2 q sub-tiles x 2 d-halves), loop-invariant; MFMA B-operand
  bf16x8 aqf[2][2];
#pragma unroll
  for (int i = 0; i < 2; i++) {
    const u16* qrow =
        qn + ((size_t)bh * 2048 + qt * 128 + w * 32 + i * 16 + l15) * 64 + lq * 8;
    aqf[i][0] = *(const bf16x8*)(qrow);
    aqf[i][1] = *(const bf16x8*)(qrow + 32);
  }

  // constant ones vector (bf16 1.0 = 0x3F80) for the lsum MFMA
  const uint4 onesu = {0x3F803F80u, 0x3F803F80u, 0x3F803F80u, 0x3F803F80u};
  const bf16x8 vones = __builtin_bit_cast(bf16x8, onesu);

  // swizzled fragment-read slot offsets (u16): slot' = (i*4+lq) ^ (l15&7), i=0..1
  int so[2];
#pragma unroll
  for (int i = 0; i < 2; i++) so[i] = ((i * 4 + lq) ^ (l15 & 7)) * 8;

  // staging: per-lane swizzled GLOBAL source, linear LDS dest (base + lane*16).
  // Both tiles are 64 rows x 64 u16 = 8 KB: 2 gld_lds rounds of 32 rows each.
  const u16* kn_b = kn + (size_t)bh * KVPAD * 64;
  const u16* vt_b = vt + (size_t)bh * 64 * KVPAD;
  const u16* ksrc[2];
  const u16* vsrc[2];
#pragma unroll
  for (int i = 0; i < 2; i++) {
    const int row = i * 32 + w * 8 + (l >> 3);
    const int sl = (l & 7) ^ (l >> 3);
    ksrc[i] = kn_b + row * 64 + sl * 8;
    vsrc[i] = vt_b + (size_t)row * KVPAD + sl * 8;
  }
  u16* kdst = &Ks[w * 512 + l * 8];
  u16* vdst = &Vs[w * 512 + l * 8];

  f32x4 O[2][4] = {};
  f32x4 lsacc[2] = {};  // lsum for sub-tile i: q=lq*4+r in reg r
  const float LOG2E = 1.44269504f;
  const float MBIAS = -8.0f * 1.44269504f;  // exp(s-8) = 2^(s*log2e + MBIAS)

  for (int kt = 0; kt < 33; kt++) {  // 33 of 34 tiles: tile 33 is all padding
    // ---- stage K (64x64) and V^T (64x64) via global_load_lds, src-swizzled ----
#pragma unroll
    for (int i = 0; i < 2; i++) {
      gld_lds16(ksrc[i] + kt * 4096, kdst + i * 2048);
      gld_lds16(vsrc[i] + kt * 64, vdst + i * 2048);
    }
    __syncthreads();  // compiler drains vmcnt before s_barrier

    // ---- S^T = K Q^T: ak read once, feeds BOTH q sub-tiles ----
    f32x4 St[2][4] = {};
    __builtin_amdgcn_s_setprio(1);
#pragma unroll
    for (int ks = 0; ks < 2; ks++)
#pragma unroll
      for (int j = 0; j < 4; j++) {
        bf16x8 ak = *(bf16x8*)&Ks[(j * 16 + l15) * 64 + so[ks]];
        St[0][j] = __builtin_amdgcn_mfma_f32_16x16x32_bf16(ak, aqf[0][ks], St[0][j], 0, 0, 0);
        St[1][j] = __builtin_amdgcn_mfma_f32_16x16x32_bf16(ak, aqf[1][ks], St[1][j], 0, 0, 0);
      }
    __builtin_amdgcn_s_setprio(0);

    // ---- P = exp(S - 8) in registers; mask pass uniform-branched; pack pa ----
    float p[2][4][4];
#pragma unroll
    for (int i = 0; i < 2; i++)
#pragma unroll
      for (int j = 0; j < 4; j++)
#pragma unroll
        for (int r = 0; r < 4; r++)
          p[i][j][r] = __builtin_amdgcn_exp2f(fmaf(St[i][j][r], LOG2E, MBIAS));
    if (kt == 32) {  // uniform branch: only kv-local 0 (global 2048) is valid
#pragma unroll
      for (int i = 0; i < 2; i++) {
#pragma unroll
        for (int j = 0; j < 4; j++)
#pragma unroll
          for (int r = 0; r < 4; r++)
            if ((j | r) != 0) p[i][j][r] = 0.f;   // compile-time for j|r != 0
        if (lq != 0) p[i][0][0] = 0.f;            // lane-dependent only here
      }
    }
    bf16x8 pa[2][2];
#pragma unroll
    for (int i = 0; i < 2; i++)
#pragma unroll
      for (int m = 0; m < 2; m++) {
        uint4 pw;
        pw.x = pk_bf16(p[i][2 * m][0], p[i][2 * m][1]);
        pw.y = pk_bf16(p[i][2 * m][2], p[i][2 * m][3]);
        pw.z = pk_bf16(p[i][2 * m + 1][0], p[i][2 * m + 1][1]);
        pw.w = pk_bf16(p[i][2 * m + 1][2], p[i][2 * m + 1][3]);
        pa[i][m] = __builtin_bit_cast(bf16x8, pw);
      }

    // ---- O += P V; lsum += P @ ones; bv read once, feeds BOTH sub-tiles ----
    __builtin_amdgcn_s_setprio(1);
#pragma unroll
    for (int m = 0; m < 2; m++) {
      lsacc[0] = __builtin_amdgcn_mfma_f32_16x16x32_bf16(pa[0][m], vones, lsacc[0], 0, 0, 0);
      lsacc[1] = __builtin_amdgcn_mfma_f32_16x16x32_bf16(pa[1][m], vones, lsacc[1], 0, 0, 0);
#pragma unroll
      for (int nt = 0; nt < 4; nt++) {
        bf16x8 bv = *(bf16x8*)&Vs[(nt * 16 + l15) * 64 + so[m]];
        O[0][nt] = __builtin_amdgcn_mfma_f32_16x16x32_bf16(pa[0][m], bv, O[0][nt], 0, 0, 0);
        O[1][nt] = __builtin_amdgcn_mfma_f32_16x16x32_bf16(pa[1][m], bv, O[1][nt], 0, 0, 0);
      }
    }
    __builtin_amdgcn_s_setprio(0);
    __syncthreads();  // K/V reads done before next staging overwrites
  }

  // ---- normalize + store (lsacc[i][r] already in O's register layout) ----
#pragma unroll
  for (int i = 0; i < 2; i++) {
    float inv[4];
#pragma unroll
    for (int r = 0; r < 4; r++) inv[r] = 1.0f / lsacc[i][r];
#pragma unroll
    for (int nt = 0; nt < 4; nt++)
#pragma unroll
      for (int r = 0; r < 4; r++) {
        int row = qt * 128 + w * 32 + i * 16 + lq * 4 + r;
        int col = h * 64 + nt * 16 + l15;
        float val = O[i][nt][r] * inv[r];
        aout[((size_t)b * 2048 + row) * 1024 + col] = f2bf(val);
      }
  }
}

// ---------------- host launch ----------------
extern "C" void kernel_launch(void* const* d_in, const int* in_sizes, int n_in,
                              void* d_out, int out_size, void* d_ws, size_t ws_size,
                              hipStream_t stream) {
  const float* x = (const float*)d_in[0];
  const float* context = (const float*)d_in[1];
  const float* g_norm = (const float*)d_in[2];
  const float* null_kv = (const float*)d_in[3];
  const float* Wq = (const float*)d_in[4];
  const float* Wkv = (const float*)d_in[5];
  const float* q_scale = (const float*)d_in[6];
  const float* k_scale = (const float*)d_in[7];
  const float* Wout = (const float*)d_in[8];
  const float* g_out = (const float*)d_in[9];
  float* out = (float*)d_out;

  char* ws = (char*)d_ws;
  u16* xn = (u16*)(ws);                      // 16,777,216 B
  u16* ctxb = (u16*)(ws + 16777216);         // 16,777,216
  u16* wqT = (u16*)(ws + 33554432);          // 2,097,152
  u16* wkvT = (u16*)(ws + 35651584);         // 4,194,304
  u16* woutT = (u16*)(ws + 39845888);        // 2,097,152
  u16* qnb = (u16*)(ws + 41943040);          // 16,777,216
  u16* knb = (u16*)(ws + 58720256);          // 17,825,792
  u16* vtb = (u16*)(ws + 76546048);          // 17,825,792
  u16* vg = (u16*)(ws + 94371840);           // 16,777,216
  float* outg = (float*)(ws + 111149056);    // 33,554,432 -> total 144,703,488
  u16* attn_out = vg;                        // vg fully consumed by v_post

  ln_kernel<true><<<8192, 256, 0, stream>>>(x, g_norm, xn);
  cast_bf16<<<8192, 256, 0, stream>>>(context, ctxb, 2097152);
  transpose_cast<<<dim3(32, 32), 256, 0, stream>>>(Wq, wqT, 1024, 1024);
  transpose_cast<<<dim3(64, 32), 256, 0, stream>>>(Wkv, wkvT, 1024, 2048);
  transpose_cast<<<dim3(32, 32), 256, 0, stream>>>(Wout, woutT, 1024, 1024);
  gemm_bt<2><<<dim3(8, 64), 256, 0, stream>>>(xn, wqT, qnb, 8192, 1024, 1024, q_scale, nullptr);
  gemm_bt<3><<<dim3(16, 64), 256, 0, stream>>>(ctxb, wkvT, knb, 8192, 2048, 1024, k_scale, vg);
  v_post<<<dim3(32, 64), 256, 0, stream>>>(vg, vtb);
  null_tail<<<64, 256, 0, stream>>>(null_kv, k_scale, knb, vtb);
  attn_kernel<<<dim3(16, 64), 256, 0, stream>>>(qnb, knb, vtb, attn_out);
  gemm_bt<0><<<dim3(8, 64), 256, 0, stream>>>(attn_out, woutT, outg, 8192, 1024, 1024, nullptr, nullptr);
  ln_kernel<false><<<8192, 256, 0, stream>>>(outg, g_out, out);
}

// Round 12
// 358.823 us; speedup vs baseline: 1.1975x; 1.1009x over previous
//
#include <hip/hip_runtime.h>

// Problem constants
#define BATCH 4
#define NSEQ 2048
#define MSEQ 2048
#define DIM 1024
#define HEADS 16
#define DHEAD 64
#define INNER 1024
#define KVLEN 2049          // null token + MSEQ
#define KVPAD 2176          // 17 * 128

typedef unsigned short u16;
typedef unsigned int u32;
typedef __bf16 bf16x8 __attribute__((ext_vector_type(8)));
typedef float f32x4 __attribute__((ext_vector_type(4)));

__device__ inline u16 f2bf(float f) {
  u32 u = __builtin_bit_cast(u32, f);
  u = (u + 0x7fffu + ((u >> 16) & 1u)) >> 16;
  return (u16)u;
}
__device__ inline float bf2f(u16 x) {
  return __builtin_bit_cast(float, (u32)x << 16);
}
// packed bf16 convert: lo -> D[15:0], hi -> D[31:16] (RNE)
__device__ inline u32 pk_bf16(float lo, float hi) {
  u32 r;
  asm("v_cvt_pk_bf16_f32 %0, %1, %2" : "=v"(r) : "v"(lo), "v"(hi));
  return r;
}

__device__ __forceinline__ void gld_lds16(const void* g, void* l) {
  __builtin_amdgcn_global_load_lds(
      (const __attribute__((address_space(1))) void*)g,
      (__attribute__((address_space(3))) void*)l, 16, 0, 0);
}

// ================= device bodies (R12: fusion refactor — logic byte-identical) =================

// ---------------- LayerNorm body (row of 1024) ----------------
template <bool OUT_BF16>
__device__ __forceinline__ void ln_body(int row, const float* __restrict__ x,
                                        const float* __restrict__ g,
                                        void* __restrict__ out, float* red) {
  const int t = threadIdx.x;
  const float4 v = ((const float4*)(x + (size_t)row * 1024))[t];
  float sum = v.x + v.y + v.z + v.w;
  float sq = v.x * v.x + v.y * v.y + v.z * v.z + v.w * v.w;
  for (int m = 1; m < 64; m <<= 1) {
    sum += __shfl_xor(sum, m, 64);
    sq += __shfl_xor(sq, m, 64);
  }
  const int w = t >> 6, l = t & 63;
  if (l == 0) { red[w] = sum; red[4 + w] = sq; }
  __syncthreads();
  sum = red[0] + red[1] + red[2] + red[3];
  sq = red[4] + red[5] + red[6] + red[7];
  const float mean = sum * (1.0f / 1024.0f);
  const float var = sq * (1.0f / 1024.0f) - mean * mean;
  const float rstd = rsqrtf(var + 1e-5f);
  const float4 gv = ((const float4*)g)[t];
  float o0 = (v.x - mean) * rstd * gv.x;
  float o1 = (v.y - mean) * rstd * gv.y;
  float o2 = (v.z - mean) * rstd * gv.z;
  float o3 = (v.w - mean) * rstd * gv.w;
  if (OUT_BF16) {
    ushort4 ov;
    ov.x = f2bf(o0); ov.y = f2bf(o1); ov.z = f2bf(o2); ov.w = f2bf(o3);
    ((ushort4*)((u16*)out + (size_t)row * 1024))[t] = ov;
  } else {
    float4 ov;
    ov.x = o0; ov.y = o1; ov.z = o2; ov.w = o3;
    ((float4*)((float*)out + (size_t)row * 1024))[t] = ov;
  }
}

// ---------------- fp32 -> bf16 cast body (8192 blocks x 256 = 2097152 float4s exact) ----------------
__device__ __forceinline__ void cast_body(int bid, const float* __restrict__ in,
                                          u16* __restrict__ out) {
  const int i = bid * 256 + threadIdx.x;
  float4 v = ((const float4*)in)[i];
  ushort4 o;
  o.x = f2bf(v.x); o.y = f2bf(v.y); o.z = f2bf(v.z); o.w = f2bf(v.w);
  ((ushort4*)out)[i] = o;
}

// ---------------- W[K][N] fp32 -> WT[N][K] bf16 (tiled transpose) body ----------------
__device__ __forceinline__ void tc_body(int bx, int by, const float* __restrict__ W,
                                        u16* __restrict__ WT, int K, int N, float* tile) {
  const int tx = threadIdx.x & 31, ty = threadIdx.x >> 5;  // ty 0..7
  const int k0 = by * 32, n0 = bx * 32;
  for (int r = ty; r < 32; r += 8) tile[r * 33 + tx] = W[(size_t)(k0 + r) * N + n0 + tx];
  __syncthreads();
  for (int r = ty; r < 32; r += 8) WT[(size_t)(n0 + r) * K + k0 + tx] = f2bf(tile[tx * 33 + r]);
}

// ---------------- null token + tail zeroing body (256 threads) ----------------
__device__ __forceinline__ void null_tail_body(int bh, const float* __restrict__ null_kv,
                                               const float* __restrict__ k_scale,
                                               u16* __restrict__ kn, u16* __restrict__ vt) {
  const int t = threadIdx.x;
  const int d = t & 63, seg = t >> 6;  // seg 0..3
  if (seg == 0) {  // one full wave: null token (needs 64-lane reduction)
    float nk = null_kv[d];
    float nv = null_kv[64 + d];
    float ss = nk * nk;
    for (int m = 1; m < 64; m <<= 1) ss += __shfl_xor(ss, m, 64);
    float inv = 1.0f / fmaxf(sqrtf(ss), 1e-12f);
    kn[((size_t)bh * KVPAD) * 64 + d] = f2bf(nk * inv * k_scale[d]);
    vt[((size_t)bh * 64 + d) * KVPAD] = f2bf(nv);  // slot(0) == 0
  }
  for (int m = KVLEN + seg; m < KVPAD; m += 4) kn[((size_t)bh * KVPAD + m) * 64 + d] = 0;
  u16* vrow = vt + ((size_t)bh * 64 + d) * KVPAD;
  for (int m = KVLEN + seg; m < KVPAD; m += 4) vrow[m] = 0;
}

// ---------------- bf16 GEMM body: C = A[M][K] @ Bt[N][K]^T ----------------
// MODE 0: fp32 C row-major. MODE 2: fused q_post -> l2norm(head)*scale*8 -> qn.
// MODE 3: fused kv post -> heads 0..15: l2norm*k_scale -> kn[b,h,m+1,64];
//                          heads 16..31: plain bf16 -> aux[row][ (h-16)*64+d ].
template <int MODE>
__device__ __forceinline__ void gemm_body(int bx, int by,
                                          const u16* __restrict__ A,
                                          const u16* __restrict__ Bt,
                                          void* __restrict__ Cv,
                                          int M, int N, int K,
                                          const float* __restrict__ scale,
                                          u16* __restrict__ aux,
                                          u16* As, u16* Bs) {
  const int t = threadIdx.x;
  const int w = t >> 6, l = t & 63, l15 = l & 15, lq = l >> 4;
  const int m0 = by * 128, n0 = bx * 128;
  const int wm = (w >> 1) * 64, wn = (w & 1) * 64;
  const int lr = l >> 2;           // 0..15 row-within-chunk
  const int lo = (l & 3) * 8;      // u16 offset within row: 0,8,16,24
  f32x4 acc[4][4] = {};
  for (int k0 = 0; k0 < K; k0 += 32) {
#pragma unroll
    for (int it = 0; it < 2; it++) {
      const int row = (w * 2 + it) * 16 + lr;   // 0..127
      gld_lds16(&A[(size_t)(m0 + row) * K + k0 + lo], &As[row * 32 + lo]);
      gld_lds16(&Bt[(size_t)(n0 + row) * K + k0 + lo], &Bs[row * 32 + lo]);
    }
    __syncthreads();
    bf16x8 af[4], bfr[4];
#pragma unroll
    for (int i = 0; i < 4; i++) af[i] = *(bf16x8*)&As[(wm + i * 16 + l15) * 32 + lq * 8];
#pragma unroll
    for (int j = 0; j < 4; j++) bfr[j] = *(bf16x8*)&Bs[(wn + j * 16 + l15) * 32 + lq * 8];
#pragma unroll
    for (int i = 0; i < 4; i++)
#pragma unroll
      for (int j = 0; j < 4; j++)
        acc[i][j] = __builtin_amdgcn_mfma_f32_16x16x32_bf16(af[i], bfr[j], acc[i][j], 0, 0, 0);
    __syncthreads();
  }

  if (MODE <= 1) {
#pragma unroll
    for (int i = 0; i < 4; i++)
#pragma unroll
      for (int j = 0; j < 4; j++)
#pragma unroll
        for (int r = 0; r < 4; r++) {
          const size_t off =
              (size_t)(m0 + wm + i * 16 + lq * 4 + r) * N + n0 + wn + j * 16 + l15;
          if (MODE == 1) ((u16*)Cv)[off] = f2bf(acc[i][j][r]);
          else ((float*)Cv)[off] = acc[i][j][r];
        }
    return;
  }

  const int head = (n0 + wn) >> 6;  // wave-uniform
  if (MODE == 3 && head >= 16) {
    // V columns: plain bf16 into compact aux[row][ (head-16)*64 + d ]
#pragma unroll
    for (int i = 0; i < 4; i++)
#pragma unroll
      for (int j = 0; j < 4; j++)
#pragma unroll
        for (int r = 0; r < 4; r++) {
          const int row = m0 + wm + i * 16 + lq * 4 + r;
          aux[(size_t)row * 1024 + (head - 16) * 64 + j * 16 + l15] = f2bf(acc[i][j][r]);
        }
    return;
  }
  // l2norm over the 64-col head + scale (q: *8)
  float sc[4];
#pragma unroll
  for (int j = 0; j < 4; j++) sc[j] = scale[j * 16 + l15];
  const float mul = (MODE == 2) ? 8.0f : 1.0f;
  u16* outp = (u16*)Cv;
#pragma unroll
  for (int i = 0; i < 4; i++)
#pragma unroll
    for (int r = 0; r < 4; r++) {
      float ss = 0.f;
#pragma unroll
      for (int j = 0; j < 4; j++) ss = fmaf(acc[i][j][r], acc[i][j][r], ss);
#pragma unroll
      for (int m = 1; m < 16; m <<= 1) ss += __shfl_xor(ss, m, 64);
      const float inv = mul / fmaxf(sqrtf(ss), 1e-12f);
      const int row = m0 + wm + i * 16 + lq * 4 + r;
      const int b = row >> 11, n = row & 2047;
      const size_t base = (MODE == 2)
          ? (((size_t)b * 16 + head) * 2048 + n) * 64
          : (((size_t)b * 16 + head) * (size_t)KVPAD + n + 1) * 64;
#pragma unroll
      for (int j = 0; j < 4; j++)
        outp[base + j * 16 + l15] = f2bf(acc[i][j][r] * inv * sc[j]);
    }
}

// ================= fused / wrapper kernels =================

// prep_fused: 6 mutually-independent pre-stages in one dispatch.
// blocks: [0,8192) ln(x); [8192,16384) cast(ctx); [16384,17408) tc(Wq);
// [17408,19456) tc(Wkv); [19456,20480) tc(Wout); [20480,20544) null_tail.
// null_tail's writes (kn slot0+tail, vt slot0+tail) are disjoint from
// gemm<3>'s (kn 1..2048) and v_post's (vt slots of abs 1..2048) -> order-free.
__global__ __launch_bounds__(256) void prep_fused(
    const float* __restrict__ x, const float* __restrict__ g_norm, u16* __restrict__ xn,
    const float* __restrict__ context, u16* __restrict__ ctxb,
    const float* __restrict__ Wq, u16* __restrict__ wqT,
    const float* __restrict__ Wkv, u16* __restrict__ wkvT,
    const float* __restrict__ Wout, u16* __restrict__ woutT,
    const float* __restrict__ null_kv, const float* __restrict__ k_scale,
    u16* __restrict__ knb, u16* __restrict__ vtb) {
  __shared__ __align__(16) float smf[1056];  // 32x33 transpose tile / ln red[8]
  int bid = blockIdx.x;
  if (bid < 8192) { ln_body<true>(bid, x, g_norm, xn, smf); return; }
  bid -= 8192;
  if (bid < 8192) { cast_body(bid, context, ctxb); return; }
  bid -= 8192;
  if (bid < 1024) { tc_body(bid & 31, bid >> 5, Wq, wqT, 1024, 1024, smf); return; }
  bid -= 1024;
  if (bid < 2048) { tc_body(bid & 63, bid >> 6, Wkv, wkvT, 1024, 2048, smf); return; }
  bid -= 2048;
  if (bid < 1024) { tc_body(bid & 31, bid >> 5, Wout, woutT, 1024, 1024, smf); return; }
  bid -= 1024;
  null_tail_body(bid, null_kv, k_scale, knb, vtb);
}

// qkv_fused: gemm<3> (KV, 1024 blocks) + gemm<2> (Q, 512 blocks) — independent;
// one dispatch packs the tails (1536 blocks = 6/CU vs 2-4/CU separately).
__global__ __launch_bounds__(256) void qkv_fused(
    const u16* __restrict__ xn, const u16* __restrict__ wqT, u16* __restrict__ qnb,
    const float* __restrict__ q_scale,
    const u16* __restrict__ ctxb, const u16* __restrict__ wkvT, u16* __restrict__ knb,
    const float* __restrict__ k_scale, u16* __restrict__ vg) {
  __shared__ __align__(16) u16 sm[128 * 32 * 2];
  const int bid = blockIdx.x;
  if (bid < 1024) {
    gemm_body<3>(bid & 15, bid >> 4, ctxb, wkvT, knb, 8192, 2048, 1024, k_scale, vg,
                 sm, sm + 128 * 32);
  } else {
    const int b2 = bid - 1024;
    gemm_body<2>(b2 & 7, b2 >> 3, xn, wqT, qnb, 8192, 1024, 1024, q_scale, nullptr,
                 sm, sm + 128 * 32);
  }
}

template <int MODE>
__global__ __launch_bounds__(256) void gemm_bt(const u16* __restrict__ A,
                                               const u16* __restrict__ Bt,
                                               void* __restrict__ Cv,
                                               int M, int N, int K,
                                               const float* __restrict__ scale,
                                               u16* __restrict__ aux) {
  __shared__ __align__(16) u16 sm[128 * 32 * 2];
  gemm_body<MODE>(blockIdx.x, blockIdx.y, A, Bt, Cv, M, N, K, scale, aux, sm, sm + 128 * 32);
}

template <bool OUT_BF16>
__global__ __launch_bounds__(256) void ln_kernel(const float* __restrict__ x,
                                                 const float* __restrict__ g,
                                                 void* __restrict__ out) {
  __shared__ float red[8];
  ln_body<OUT_BF16>(blockIdx.x, x, g, out, red);
}

// ---------------- v post: transpose vg[row][h*64+d] -> vt[b,h,64,KVPAD] ----------------
// The KV (column) index is stored k-PERMUTED within each 128-aligned block
// by the bit-permutation matching the in-register P fragments of attn_kernel:
//   forward g(slot): [s6 s5 s4 s3 s2 s1 s0] -> kv-local [s6 s5 s2 s4 s3 s1 s0]
//   inverse slot(a) = (a & 0x63) | ((a & 0x10) >> 2) | ((a & 0x0C) << 1)
// slot() keeps bits 0,1,5,6 fixed -> maps every 64-aligned block onto itself
// (required by attn's KVBLK=64 tiling). slot(0)=0 -> null_tail untouched.
__global__ __launch_bounds__(256) void v_post(const u16* __restrict__ vg,
                                              u16* __restrict__ vt) {
  __shared__ u16 tile[64][68];
  const int bh = blockIdx.y, mt = blockIdx.x;
  const int tx = threadIdx.x & 63, ty = threadIdx.x >> 6;
  const int b = bh >> 4, h = bh & 15;
  const int m0 = mt * 64;
  for (int r = ty; r < 64; r += 4)
    tile[tx][r] = vg[(size_t)(b * 2048 + m0 + r) * 1024 + h * 64 + tx];
  __syncthreads();
  const int abs_ = 1 + m0 + tx;
  const int a = abs_ & 127;
  const int slot = (abs_ & ~127) | (a & 0x63) | ((a & 0x10) >> 2) | ((a & 0x0C) << 1);
  for (int d = ty; d < 64; d += 4)
    vt[((size_t)bh * 64 + d) * KVPAD + slot] = tile[d][tx];
}

// ---------------- flash attention, fixed-max softmax (R11-verbatim, known-pass) ----------------
// |sim| <= 8 by Cauchy-Schwarz (l2norm'd q,k; scales==1; SCALE=8) -> static max 8.
// SWAPPED QK^T (D = S^T, P in registers via v_cvt_pk_bf16_f32), V rows
// g-permuted (v_post), lsum on the MFMA pipe via mfma(pa, ones), 32 q-rows/wave
// (each ak/bv LDS read feeds 2 MFMAs), KVBLK=64, staging via global_load_lds
// with source-side bank swizzle (measured conflict-free), s_setprio around
// MFMA clusters. 81.2us in R11 (MfmaUtil 42.5, VALUBusy 49.8, VGPR 64).
// History: R5 direct-global fragments 3.6x WORSE; R9 launch_bounds(256,8)
// spilled (WRITE_SIZE jump = falsifier); R10 occupancy lever null.
__global__ __launch_bounds__(256, 4) void attn_kernel(const u16* __restrict__ qn,
                                                      const u16* __restrict__ kn,
                                                      const u16* __restrict__ vt,
                                                      u16* __restrict__ aout) {
  __shared__ __align__(16) u16 Ks[64 * 64];  // K tile (linear, src-swizzled)
  __shared__ __align__(16) u16 Vs[64 * 64];  // V^T tile (linear, src-swizzled, g-permuted kv)
  const int qt = blockIdx.x, bh = blockIdx.y;
  const int b = bh >> 4, h = bh & 15;
  const int t = threadIdx.x, w = t >> 6, l = t & 63, l15 = l & 15, lq = l >> 4;

  // Q fragments (2 q sub-tiles x 2 d-halves), loop-invariant; MFMA B-operand
  bf16x8 aqf[2][2];
#pragma unroll
  for (int i = 0; i < 2; i++) {
    const u16* qrow =
        qn + ((size_t)bh * 2048 + qt * 128 + w * 32 + i * 16 + l15) * 64 + lq * 8;
    aqf[i][0] = *(const bf16x8*)(qrow);
    aqf[i][1] = *(const bf16x8*)(qrow + 32);
  }

  // constant ones vector (bf16 1.0 = 0x3F80) for the lsum MFMA
  const uint4 onesu = {0x3F803F80u, 0x3F803F80u, 0x3F803F80u, 0x3F803F80u};
  const bf16x8 vones = __builtin_bit_cast(bf16x8, onesu);

  // swizzled fragment-read slot offsets (u16): slot' = (i*4+lq) ^ (l15&7), i=0..1
  int so[2];
#pragma unroll
  for (int i = 0; i < 2; i++) so[i] = ((i * 4 + lq) ^ (l15 & 7)) * 8;

  // staging: per-lane swizzled GLOBAL source, linear LDS dest (base + lane*16).
  const u16* kn_b = kn + (size_t)bh * KVPAD * 64;
  const u16* vt_b = vt + (size_t)bh * 64 * KVPAD;
  const u16* ksrc[2];
  const u16* vsrc[2];
#pragma unroll
  for (int i = 0; i < 2; i++) {
    const int row = i * 32 + w * 8 + (l >> 3);
    const int sl = (l & 7) ^ (l >> 3);
    ksrc[i] = kn_b + row * 64 + sl * 8;
    vsrc[i] = vt_b + (size_t)row * KVPAD + sl * 8;
  }
  u16* kdst = &Ks[w * 512 + l * 8];
  u16* vdst = &Vs[w * 512 + l * 8];

  f32x4 O[2][4] = {};
  f32x4 lsacc[2] = {};  // lsum for sub-tile i: q=lq*4+r in reg r
  const float LOG2E = 1.44269504f;
  const float MBIAS = -8.0f * 1.44269504f;  // exp(s-8) = 2^(s*log2e + MBIAS)

  for (int kt = 0; kt < 33; kt++) {  // 33 of 34 tiles: tile 33 is all padding
    // ---- stage K (64x64) and V^T (64x64) via global_load_lds, src-swizzled ----
#pragma unroll
    for (int i = 0; i < 2; i++) {
      gld_lds16(ksrc[i] + kt * 4096, kdst + i * 2048);
      gld_lds16(vsrc[i] + kt * 64, vdst + i * 2048);
    }
    __syncthreads();  // compiler drains vmcnt before s_barrier

    // ---- S^T = K Q^T: ak read once, feeds BOTH q sub-tiles ----
    f32x4 St[2][4] = {};
    __builtin_amdgcn_s_setprio(1);
#pragma unroll
    for (int ks = 0; ks < 2; ks++)
#pragma unroll
      for (int j = 0; j < 4; j++) {
        bf16x8 ak = *(bf16x8*)&Ks[(j * 16 + l15) * 64 + so[ks]];
        St[0][j] = __builtin_amdgcn_mfma_f32_16x16x32_bf16(ak, aqf[0][ks], St[0][j], 0, 0, 0);
        St[1][j] = __builtin_amdgcn_mfma_f32_16x16x32_bf16(ak, aqf[1][ks], St[1][j], 0, 0, 0);
      }
    __builtin_amdgcn_s_setprio(0);

    // ---- P = exp(S - 8) in registers; mask pass uniform-branched; pack pa ----
    float p[2][4][4];
#pragma unroll
    for (int i = 0; i < 2; i++)
#pragma unroll
      for (int j = 0; j < 4; j++)
#pragma unroll
        for (int r = 0; r < 4; r++)
          p[i][j][r] = __builtin_amdgcn_exp2f(fmaf(St[i][j][r], LOG2E, MBIAS));
    if (kt == 32) {  // uniform branch: only kv-local 0 (global 2048) is valid
#pragma unroll
      for (int i = 0; i < 2; i++) {
#pragma unroll
        for (int j = 0; j < 4; j++)
#pragma unroll
          for (int r = 0; r < 4; r++)
            if ((j | r) != 0) p[i][j][r] = 0.f;   // compile-time for j|r != 0
        if (lq != 0) p[i][0][0] = 0.f;            // lane-dependent only here
      }
    }
    bf16x8 pa[2][2];
#pragma unroll
    for (int i = 0; i < 2; i++)
#pragma unroll
      for (int m = 0; m < 2; m++) {
        uint4 pw;
        pw.x = pk_bf16(p[i][2 * m][0], p[i][2 * m][1]);
        pw.y = pk_bf16(p[i][2 * m][2], p[i][2 * m][3]);
        pw.z = pk_bf16(p[i][2 * m + 1][0], p[i][2 * m + 1][1]);
        pw.w = pk_bf16(p[i][2 * m + 1][2], p[i][2 * m + 1][3]);
        pa[i][m] = __builtin_bit_cast(bf16x8, pw);
      }

    // ---- O += P V; lsum += P @ ones; bv read once, feeds BOTH sub-tiles ----
    __builtin_amdgcn_s_setprio(1);
#pragma unroll
    for (int m = 0; m < 2; m++) {
      lsacc[0] = __builtin_amdgcn_mfma_f32_16x16x32_bf16(pa[0][m], vones, lsacc[0], 0, 0, 0);
      lsacc[1] = __builtin_amdgcn_mfma_f32_16x16x32_bf16(pa[1][m], vones, lsacc[1], 0, 0, 0);
#pragma unroll
      for (int nt = 0; nt < 4; nt++) {
        bf16x8 bv = *(bf16x8*)&Vs[(nt * 16 + l15) * 64 + so[m]];
        O[0][nt] = __builtin_amdgcn_mfma_f32_16x16x32_bf16(pa[0][m], bv, O[0][nt], 0, 0, 0);
        O[1][nt] = __builtin_amdgcn_mfma_f32_16x16x32_bf16(pa[1][m], bv, O[1][nt], 0, 0, 0);
      }
    }
    __builtin_amdgcn_s_setprio(0);
    __syncthreads();  // K/V reads done before next staging overwrites
  }

  // ---- normalize + store (lsacc[i][r] already in O's register layout) ----
#pragma unroll
  for (int i = 0; i < 2; i++) {
    float inv[4];
#pragma unroll
    for (int r = 0; r < 4; r++) inv[r] = 1.0f / lsacc[i][r];
#pragma unroll
    for (int nt = 0; nt < 4; nt++)
#pragma unroll
      for (int r = 0; r < 4; r++) {
        int row = qt * 128 + w * 32 + i * 16 + lq * 4 + r;
        int col = h * 64 + nt * 16 + l15;
        float val = O[i][nt][r] * inv[r];
        aout[((size_t)b * 2048 + row) * 1024 + col] = f2bf(val);
      }
  }
}

// ---------------- host launch ----------------
extern "C" void kernel_launch(void* const* d_in, const int* in_sizes, int n_in,
                              void* d_out, int out_size, void* d_ws, size_t ws_size,
                              hipStream_t stream) {
  const float* x = (const float*)d_in[0];
  const float* context = (const float*)d_in[1];
  const float* g_norm = (const float*)d_in[2];
  const float* null_kv = (const float*)d_in[3];
  const float* Wq = (const float*)d_in[4];
  const float* Wkv = (const float*)d_in[5];
  const float* q_scale = (const float*)d_in[6];
  const float* k_scale = (const float*)d_in[7];
  const float* Wout = (const float*)d_in[8];
  const float* g_out = (const float*)d_in[9];
  float* out = (float*)d_out;

  char* ws = (char*)d_ws;
  u16* xn = (u16*)(ws);                      // 16,777,216 B
  u16* ctxb = (u16*)(ws + 16777216);         // 16,777,216
  u16* wqT = (u16*)(ws + 33554432);          // 2,097,152
  u16* wkvT = (u16*)(ws + 35651584);         // 4,194,304
  u16* woutT = (u16*)(ws + 39845888);        // 2,097,152
  u16* qnb = (u16*)(ws + 41943040);          // 16,777,216
  u16* knb = (u16*)(ws + 58720256);          // 17,825,792
  u16* vtb = (u16*)(ws + 76546048);          // 17,825,792
  u16* vg = (u16*)(ws + 94371840);           // 16,777,216
  float* outg = (float*)(ws + 111149056);    // 33,554,432 -> total 144,703,488
  u16* attn_out = vg;                        // vg fully consumed by v_post

  // 6 dispatches (was 12): prep(ln+cast+3xtranspose+null_tail) -> qkv(gemm3+gemm2)
  // -> v_post -> attn -> gemm0 -> ln_out
  prep_fused<<<20544, 256, 0, stream>>>(x, g_norm, xn, context, ctxb,
                                        Wq, wqT, Wkv, wkvT, Wout, woutT,
                                        null_kv, k_scale, knb, vtb);
  qkv_fused<<<1536, 256, 0, stream>>>(xn, wqT, qnb, q_scale, ctxb, wkvT, knb, k_scale, vg);
  v_post<<<dim3(32, 64), 256, 0, stream>>>(vg, vtb);
  attn_kernel<<<dim3(16, 64), 256, 0, stream>>>(qnb, knb, vtb, attn_out);
  gemm_bt<0><<<dim3(8, 64), 256, 0, stream>>>(attn_out, woutT, outg, 8192, 1024, 1024, nullptr, nullptr);
  ln_kernel<false><<<8192, 256, 0, stream>>>(outg, g_out, out);
}